// Round 5
// baseline (5889.969 us; speedup 1.0000x reference)
//
#include <hip/hip_runtime.h>
#include <hip/hip_bf16.h>

// CustomLSTM: B=128, T=1024, D=256, U=256, fp32 in/out.
// Round 4 (resubmit; round 4 bench = acquisition timeout, no data):
//  - wreg chunks pinned via asm volatile("" : "+v") after load: compiler can
//    no longer re-stream them from L2 each step (rounds 2/3: VGPR_Count=128
//    proved it sank the loads; budget attributes alone don't stop that).
//  - Gate-phase split (chunk order c8 = h*4+g): GEMM half / elementwise half
//    interleave halves acc pressure (16 live accs) and overlaps VALU w/ MFMA.
//  - hA double-buffer (two named LDS buffers, 2-step unrolled loop): one
//    barrier per step, all-static addressing.
//  - NLDS=18 (144 KB) + 2x8 KB hA = 160 KB LDS; NREG=46 (184 pinned VGPRs).
// 8 blocks x 16 batches; no inter-block communication anywhere.

#define B_ 128
#define T_ 1024
#define D_ 256
#define U_ 256

#define NLDS 18          // chunks per wave in LDS   (144 KB block total)
#define NREG 46          // chunks per wave in VGPRs (184 VGPRs, asm-pinned)

#define HALL ((size_t)B_ * T_ * U_)

using short8  = __attribute__((ext_vector_type(8))) short;   // 8 bf16 (4 VGPRs)
using float4v = __attribute__((ext_vector_type(4))) float;   // 4 fp32 acc

__device__ inline unsigned short f2bf(float f) {
    unsigned int u = __float_as_uint(f);
    unsigned int r = (u + 0x7FFFu + ((u >> 16) & 1u)) >> 16;
    return (unsigned short)r;
}
__device__ inline float bflo(unsigned int v) { return __uint_as_float(v << 16); }
__device__ inline float bfhi(unsigned int v) { return __uint_as_float(v & 0xffff0000u); }
__device__ inline float sigm(float z)  { return 1.0f / (1.0f + __expf(-z)); }
__device__ inline float tanh_f(float z){ float e = __expf(2.0f * z); return 1.0f - 2.0f / (e + 1.0f); }

// ---------------------------------------------------------------------------
// Pack 8 matrices [256][256] fp32 (row k, col u) into bf16 MFMA B-fragments.
// chunk = (w*8 + ks)*8 + c8,  c8 = h*4 + g  (h = u-half, g = gate f/i/c/o).
// chunk = 512 shorts (64 lanes x 8).
// Lane l of chunk holds  M[k = ks*32 + (l>>4)*8 + j][u = w*32 + h*16 + (l&15)].
// pack0 (offset 0 shorts)      = Uf,Ui,Uc,Uo   (recurrent)
// pack1 (offset 262144 shorts) = Wf,Wi,Wc,Wo   (input proj)
// ---------------------------------------------------------------------------
__global__ __launch_bounds__(256) void pack_kernel(
    const float* __restrict__ Uf, const float* __restrict__ Ui,
    const float* __restrict__ Uc, const float* __restrict__ Uo,
    const float* __restrict__ Wf, const float* __restrict__ Wi,
    const float* __restrict__ Wc, const float* __restrict__ Wo,
    short* __restrict__ ws)
{
    int q = blockIdx.x * 256 + threadIdx.x;      // 0..65535
    int p     = q >> 15;                          // 0: U-pack, 1: W-pack
    int rem   = q & 32767;
    int chunk = rem >> 6;                         // 0..511
    int l     = rem & 63;
    int c8 = chunk & 7;
    int g  = c8 & 3;                              // gate (f,i,c,o)
    int h  = c8 >> 2;                             // u-half
    int ks = (chunk >> 3) & 7;
    int w  = chunk >> 6;

    const float* mats[8] = {Uf, Ui, Uc, Uo, Wf, Wi, Wc, Wo};
    const float* M = mats[p * 4 + g];

    int u = w * 32 + h * 16 + (l & 15);
    int k = ks * 32 + ((l >> 4) << 3);
    const float* s = M + (size_t)k * 256 + u;

    short8 fr;
#pragma unroll
    for (int j = 0; j < 8; ++j) fr[j] = (short)f2bf(s[(size_t)j * 256]);

    short* dst = ws + (size_t)p * 262144 + (size_t)chunk * 512 + l * 8;
    *reinterpret_cast<short8*>(dst) = fr;
}

// ---------------------------------------------------------------------------
// proj: zx[t][b][u][g] (bf16, g minor, bias folded) = sum_k x[b][t][k]*W_g[k][u] + b_g[u]
// M-tile = 64 rows per block; streams W-pack fragments from L2.
// ---------------------------------------------------------------------------
__global__ __launch_bounds__(512, 2) void proj_kernel(
    const float* __restrict__ x, const short* __restrict__ wpack,
    const float* __restrict__ bfv, const float* __restrict__ biv,
    const float* __restrict__ bcv, const float* __restrict__ bov,
    short* __restrict__ zx)
{
    __shared__ short aF[4 * 8 * 512];  // 4 M-sub x 8 ks chunks (32KB)
    const int tid = threadIdx.x;
    const int w = tid >> 6, l = tid & 63;
    const long m0 = (long)blockIdx.x * 64;

    // stage A fragments: x rows m0..m0+63, bf16
#pragma unroll
    for (int rep = 0; rep < 4; ++rep) {
        int slot = tid + rep * 512;      // 0..2047
        int ms = slot >> 9;
        int rem = slot & 511;
        int ks = rem >> 6;
        int ll = rem & 63;
        long mm = m0 + ms * 16 + (ll & 15);
        int k = ks * 32 + ((ll >> 4) << 3);
        const float* s = x + (size_t)mm * 256 + k;
        float4 v0 = *reinterpret_cast<const float4*>(s);
        float4 v1 = *reinterpret_cast<const float4*>(s + 4);
        short8 fr;
        fr[0] = (short)f2bf(v0.x); fr[1] = (short)f2bf(v0.y);
        fr[2] = (short)f2bf(v0.z); fr[3] = (short)f2bf(v0.w);
        fr[4] = (short)f2bf(v1.x); fr[5] = (short)f2bf(v1.y);
        fr[6] = (short)f2bf(v1.z); fr[7] = (short)f2bf(v1.w);
        *reinterpret_cast<short8*>(&aF[(ms * 8 + ks) * 512 + ll * 8]) = fr;
    }
    __syncthreads();

    float4v acc[4][8];
#pragma unroll
    for (int ms = 0; ms < 4; ++ms)
#pragma unroll
        for (int c8 = 0; c8 < 8; ++c8) acc[ms][c8] = (float4v){0.f, 0.f, 0.f, 0.f};

    const short* base = wpack + (size_t)w * 64 * 512;
#pragma unroll
    for (int ks = 0; ks < 8; ++ks) {
        short8 a[4];
#pragma unroll
        for (int ms = 0; ms < 4; ++ms)
            a[ms] = *reinterpret_cast<const short8*>(&aF[(ms * 8 + ks) * 512 + l * 8]);
#pragma unroll
        for (int c8 = 0; c8 < 8; ++c8) {
            short8 bfr = *reinterpret_cast<const short8*>(base + (size_t)(ks * 8 + c8) * 512 + l * 8);
#pragma unroll
            for (int ms = 0; ms < 4; ++ms)
                acc[ms][c8] = __builtin_amdgcn_mfma_f32_16x16x32_bf16(a[ms], bfr, acc[ms][c8], 0, 0, 0);
        }
    }

    // write zx: 4 gates packed per (m,u): 8 bytes; bias folded in fp32.
    // chunk order: gate g, half h lives at c8 = h*4 + g.
#pragma unroll
    for (int ms = 0; ms < 4; ++ms)
#pragma unroll
        for (int h = 0; h < 2; ++h)
#pragma unroll
            for (int j = 0; j < 4; ++j) {
                size_t mm = (size_t)(m0 + ms * 16 + ((l >> 4) << 2) + j);
                int u = w * 32 + h * 16 + (l & 15);
                size_t b = mm >> 10;          // mm = b*T + t
                size_t t = mm & 1023;
                unsigned int g0 = f2bf(acc[ms][h * 4 + 0][j] + bfv[u]);
                unsigned int g1 = f2bf(acc[ms][h * 4 + 1][j] + biv[u]);
                unsigned int g2 = f2bf(acc[ms][h * 4 + 2][j] + bcv[u]);
                unsigned int g3 = f2bf(acc[ms][h * 4 + 3][j] + bov[u]);
                uint2 v;
                v.x = g0 | (g1 << 16);
                v.y = g2 | (g3 << 16);
                *reinterpret_cast<uint2*>(zx + (t * B_ + b) * 1024 + (size_t)u * 4) = v;
            }
}

// ---------------------------------------------------------------------------
// Elementwise LSTM gate phase for u-half h: consumes 4 accs (f,i,c,o),
// updates cell state, writes out + restages h into dst A-fragment buffer.
// ---------------------------------------------------------------------------
__device__ __forceinline__ void ew_phase(
    int h, int t, const float4v ac[4], const uint2 zch[4], float (&csth)[4],
    short* dst, float* __restrict__ out, int b0, int w, int col, int rg)
{
#pragma unroll
    for (int j = 0; j < 4; ++j) {
        uint2 v = zch[j];
        float zf = ac[0][j] + bflo(v.x);
        float zi = ac[1][j] + bfhi(v.x);
        float zc = ac[2][j] + bflo(v.y);
        float zo = ac[3][j] + bfhi(v.y);
        float fg = sigm(zf), ig = sigm(zi), og = sigm(zo);
        float cg = tanh_f(zc);
        float cn = fg * csth[j] + ig * cg;
        csth[j] = cn;
        float hn = og * tanh_f(cn);

        int bb = b0 + rg * 4 + j;
        int u = w * 32 + h * 16 + col;
        out[((size_t)bb * T_ + t) * 256 + u] = hn;
        if (t == T_ - 1) {
            out[HALL + (size_t)bb * 256 + u] = hn;
            out[HALL + (size_t)B_ * U_ + (size_t)bb * 256 + u] = cn;
        }
        // restage h into A-fragment layout (k-index = u)
        int ks2 = u >> 5;
        int s2 = (rg * 4 + j) + 16 * ((u >> 3) & 3);
        dst[ks2 * 512 + s2 * 8 + (u & 7)] = (short)f2bf(hn);
    }
}

// One full LSTM step: reads h A-frags from src, writes new ones to dst.
__device__ __forceinline__ void lstm_step(
    int t, const short* src, short* dst, const short* wl,
    const short8 (&wreg)[NREG], const short* __restrict__ zx,
    float* __restrict__ out, float (&cst)[2][4],
    int b0, int w, int l, int col, int rg)
{
    // this step's input projections (independent of src; loads issue early)
    uint2 zc[2][4];
#pragma unroll
    for (int h = 0; h < 2; ++h)
#pragma unroll
        for (int j = 0; j < 4; ++j) {
            size_t bb = (size_t)(b0 + rg * 4 + j);
            int u = w * 32 + h * 16 + col;
            zc[h][j] = *reinterpret_cast<const uint2*>(
                zx + ((size_t)t * B_ + bb) * 1024 + (size_t)u * 4);
        }

    // ---- half A: u-low 16 cols, gates f,i,c,o (chunks q = ks*8 + 0..3) ----
    float4v ac[4];
#pragma unroll
    for (int g = 0; g < 4; ++g) ac[g] = (float4v){0.f, 0.f, 0.f, 0.f};
#pragma unroll
    for (int ks = 0; ks < 8; ++ks) {
        short8 a = *reinterpret_cast<const short8*>(&src[ks * 512 + l * 8]);
#pragma unroll
        for (int g = 0; g < 4; ++g) {
            const int q = ks * 8 + g;
            short8 bv;
            if (q < NLDS)
                bv = *reinterpret_cast<const short8*>(&wl[(w * NLDS + q) * 512 + l * 8]);
            else
                bv = wreg[q - NLDS];
            ac[g] = __builtin_amdgcn_mfma_f32_16x16x32_bf16(a, bv, ac[g], 0, 0, 0);
        }
    }
    ew_phase(0, t, ac, zc[0], cst[0], dst, out, b0, w, col, rg);

    // ---- half B: u-high 16 cols (chunks q = ks*8 + 4..7) ----
    float4v ac2[4];
#pragma unroll
    for (int g = 0; g < 4; ++g) ac2[g] = (float4v){0.f, 0.f, 0.f, 0.f};
#pragma unroll
    for (int ks = 0; ks < 8; ++ks) {
        short8 a = *reinterpret_cast<const short8*>(&src[ks * 512 + l * 8]);
#pragma unroll
        for (int g = 0; g < 4; ++g) {
            const int q = ks * 8 + 4 + g;
            short8 bv;
            if (q < NLDS)
                bv = *reinterpret_cast<const short8*>(&wl[(w * NLDS + q) * 512 + l * 8]);
            else
                bv = wreg[q - NLDS];
            ac2[g] = __builtin_amdgcn_mfma_f32_16x16x32_bf16(a, bv, ac2[g], 0, 0, 0);
        }
    }
    ew_phase(1, t, ac2, zc[1], cst[1], dst, out, b0, w, col, rg);
}

// ---------------------------------------------------------------------------
// Resident scan. 8 blocks x 512 threads; block owns batches [b0, b0+16).
// Chunks q<NLDS in LDS; q>=NLDS in VGPRs, pinned live via asm.
// ---------------------------------------------------------------------------
__global__ __launch_bounds__(512, 2) void lstm_scan_res(
    const float* __restrict__ h0, const float* __restrict__ c0,
    const short* __restrict__ upack, const short* __restrict__ zx,
    float* __restrict__ out)
{
    __shared__ short wlds[NLDS * 8 * 512];   // 144 KB weight chunks
    __shared__ short hAa[4096];              // 8 KB h A-fragments (even steps src)
    __shared__ short hAb[4096];              // 8 KB h A-fragments (odd steps src)

    const int tid = threadIdx.x;
    const int w = tid >> 6, l = tid & 63;
    const int b0 = blockIdx.x * 16;
    const int col = l & 15, rg = l >> 4;

    // one-time: stage this wave's LDS chunks and load its register chunks
    const short* baseU = upack + (size_t)w * 64 * 512 + (size_t)l * 8;
#pragma unroll
    for (int q = 0; q < NLDS; ++q)
        *reinterpret_cast<short8*>(&wlds[((size_t)w * NLDS + q) * 512 + l * 8]) =
            *reinterpret_cast<const short8*>(baseU + (size_t)q * 512);

    short8 wreg[NREG];
#pragma unroll
    for (int r = 0; r < NREG; ++r)
        wreg[r] = *reinterpret_cast<const short8*>(baseU + (size_t)(NLDS + r) * 512);
    // Pin: asm may "modify" each value -> reloading from memory is illegal ->
    // chunks must stay live in VGPRs across the whole t-loop.
#pragma unroll
    for (int r = 0; r < NREG; ++r)
        asm volatile("" : "+v"(wreg[r]));

    float cst[2][4];
#pragma unroll
    for (int h = 0; h < 2; ++h)
#pragma unroll
        for (int j = 0; j < 4; ++j)
            cst[h][j] = c0[(size_t)(b0 + rg * 4 + j) * 256 + (w * 32 + h * 16 + col)];

    // stage h0 as A-fragments into hAa (wave w stages ks-chunk w)
    {
        int ks = w;
        int bb = b0 + col;
        int k = ks * 32 + rg * 8;
        const float* s = h0 + (size_t)bb * 256 + k;
        float4 v0 = *reinterpret_cast<const float4*>(s);
        float4 v1 = *reinterpret_cast<const float4*>(s + 4);
        short8 fr;
        fr[0] = (short)f2bf(v0.x); fr[1] = (short)f2bf(v0.y);
        fr[2] = (short)f2bf(v0.z); fr[3] = (short)f2bf(v0.w);
        fr[4] = (short)f2bf(v1.x); fr[5] = (short)f2bf(v1.y);
        fr[6] = (short)f2bf(v1.z); fr[7] = (short)f2bf(v1.w);
        *reinterpret_cast<short8*>(&hAa[ks * 512 + l * 8]) = fr;
    }
    __syncthreads();

#pragma unroll 1
    for (int t = 0; t < T_; t += 2) {
        lstm_step(t,     hAa, hAb, wlds, wreg, zx, out, cst, b0, w, l, col, rg);
        __syncthreads();
        lstm_step(t + 1, hAb, hAa, wlds, wreg, zx, out, cst, b0, w, l, col, rg);
        __syncthreads();
    }
}

// ---------------------------------------------------------------------------
// Fallback fused scan (workspace too small for zx): streams U and W packs
// from L2 every step. Slow but correct. (Gate order: c8 = h*4 + g.)
// ---------------------------------------------------------------------------
__global__ __launch_bounds__(512, 2) void lstm_scan_fused(
    const float* __restrict__ x,
    const float* __restrict__ h0, const float* __restrict__ c0,
    const float* __restrict__ bfv, const float* __restrict__ biv,
    const float* __restrict__ bcv, const float* __restrict__ bov,
    const short* __restrict__ upack, const short* __restrict__ wpack,
    float* __restrict__ out)
{
    __shared__ short hA[4096];
    __shared__ short xA[4096];

    const int tid = threadIdx.x;
    const int w = tid >> 6, l = tid & 63;
    const int b0 = blockIdx.x * 16;
    const int col = l & 15, rg = l >> 4;

    float bias[4][2];
#pragma unroll
    for (int h = 0; h < 2; ++h) {
        int u = w * 32 + h * 16 + col;
        bias[0][h] = bfv[u]; bias[1][h] = biv[u];
        bias[2][h] = bcv[u]; bias[3][h] = bov[u];
    }
    float cst[2][4];
#pragma unroll
    for (int h = 0; h < 2; ++h)
#pragma unroll
        for (int j = 0; j < 4; ++j)
            cst[h][j] = c0[(size_t)(b0 + rg * 4 + j) * 256 + (w * 32 + h * 16 + col)];

    {
        int ks = w;
        int bb = b0 + col;
        int k = ks * 32 + rg * 8;
        const float* s = h0 + (size_t)bb * 256 + k;
        float4 v0 = *reinterpret_cast<const float4*>(s);
        float4 v1 = *reinterpret_cast<const float4*>(s + 4);
        short8 fr;
        fr[0] = (short)f2bf(v0.x); fr[1] = (short)f2bf(v0.y);
        fr[2] = (short)f2bf(v0.z); fr[3] = (short)f2bf(v0.w);
        fr[4] = (short)f2bf(v1.x); fr[5] = (short)f2bf(v1.y);
        fr[6] = (short)f2bf(v1.z); fr[7] = (short)f2bf(v1.w);
        *reinterpret_cast<short8*>(&hA[ks * 512 + l * 8]) = fr;
    }
    __syncthreads();

    const short* baseU = upack + (size_t)w * 64 * 512;
    const short* baseW = wpack + (size_t)w * 64 * 512;

#pragma unroll 1
    for (int t = 0; t < T_; ++t) {
        float4v acc[8];
#pragma unroll
        for (int i = 0; i < 8; ++i) acc[i] = (float4v){0.f, 0.f, 0.f, 0.f};

        {
            int bb = b0 + col;
            int k = w * 32 + rg * 8;
            const float* s = x + ((size_t)bb * T_ + t) * 256 + k;
            float4 v0 = *reinterpret_cast<const float4*>(s);
            float4 v1 = *reinterpret_cast<const float4*>(s + 4);
            short8 fr;
            fr[0] = (short)f2bf(v0.x); fr[1] = (short)f2bf(v0.y);
            fr[2] = (short)f2bf(v0.z); fr[3] = (short)f2bf(v0.w);
            fr[4] = (short)f2bf(v1.x); fr[5] = (short)f2bf(v1.y);
            fr[6] = (short)f2bf(v1.z); fr[7] = (short)f2bf(v1.w);
            *reinterpret_cast<short8*>(&xA[w * 512 + l * 8]) = fr;
            __syncthreads();
        }

#pragma unroll
        for (int ks = 0; ks < 8; ++ks) {
            short8 a = *reinterpret_cast<const short8*>(&hA[ks * 512 + l * 8]);
#pragma unroll
            for (int c8 = 0; c8 < 8; ++c8) {
                short8 bfr = *reinterpret_cast<const short8*>(baseU + (size_t)(ks * 8 + c8) * 512 + l * 8);
                acc[c8] = __builtin_amdgcn_mfma_f32_16x16x32_bf16(a, bfr, acc[c8], 0, 0, 0);
            }
        }
#pragma unroll
        for (int ks = 0; ks < 8; ++ks) {
            short8 a = *reinterpret_cast<const short8*>(&xA[ks * 512 + l * 8]);
#pragma unroll
            for (int c8 = 0; c8 < 8; ++c8) {
                short8 bfr = *reinterpret_cast<const short8*>(baseW + (size_t)(ks * 8 + c8) * 512 + l * 8);
                acc[c8] = __builtin_amdgcn_mfma_f32_16x16x32_bf16(a, bfr, acc[c8], 0, 0, 0);
            }
        }
        __syncthreads();

#pragma unroll
        for (int h = 0; h < 2; ++h)
#pragma unroll
            for (int j = 0; j < 4; ++j) {
                float zf = acc[h * 4 + 0][j] + bias[0][h];
                float zi = acc[h * 4 + 1][j] + bias[1][h];
                float zc = acc[h * 4 + 2][j] + bias[2][h];
                float zo = acc[h * 4 + 3][j] + bias[3][h];
                float fg = sigm(zf), ig = sigm(zi), og = sigm(zo);
                float cg = tanh_f(zc);
                float cn = fg * cst[h][j] + ig * cg;
                cst[h][j] = cn;
                float hn = og * tanh_f(cn);

                int bb = b0 + rg * 4 + j;
                int u = w * 32 + h * 16 + col;
                out[((size_t)bb * T_ + t) * 256 + u] = hn;
                if (t == T_ - 1) {
                    out[HALL + (size_t)bb * 256 + u] = hn;
                    out[HALL + (size_t)B_ * U_ + (size_t)bb * 256 + u] = cn;
                }
                int ks2 = u >> 5;
                int s2 = (rg * 4 + j) + 16 * ((u >> 3) & 3);
                hA[ks2 * 512 + s2 * 8 + (u & 7)] = (short)f2bf(hn);
            }
        __syncthreads();
    }
}

extern "C" void kernel_launch(void* const* d_in, const int* in_sizes, int n_in,
                              void* d_out, int out_size, void* d_ws, size_t ws_size,
                              hipStream_t stream) {
    const float* x  = (const float*)d_in[0];
    const float* h0 = (const float*)d_in[1];
    const float* c0 = (const float*)d_in[2];
    const float* Wf = (const float*)d_in[3];
    const float* Uf = (const float*)d_in[4];
    const float* bf = (const float*)d_in[5];
    const float* Wi = (const float*)d_in[6];
    const float* Ui = (const float*)d_in[7];
    const float* bi = (const float*)d_in[8];
    const float* Wc = (const float*)d_in[9];
    const float* Uc = (const float*)d_in[10];
    const float* bc = (const float*)d_in[11];
    const float* Wo = (const float*)d_in[12];
    const float* Uo = (const float*)d_in[13];
    const float* bo = (const float*)d_in[14];

    short* ws    = (short*)d_ws;
    short* upack = ws;                 // 512 KB
    short* wpack = ws + 262144;        // 512 KB
    short* zx    = ws + 524288;        // 268.4 MB (bf16 [T][B][U][4])

    const size_t need = 1048576ull + (size_t)B_ * T_ * U_ * 4 * 2;
    const bool fused = ws_size < need;

    hipLaunchKernelGGL(pack_kernel, dim3(256), dim3(256), 0, stream,
                       Uf, Ui, Uc, Uo, Wf, Wi, Wc, Wo, ws);

    float* out = (float*)d_out;
    if (!fused) {
        hipLaunchKernelGGL(proj_kernel, dim3((B_ * T_) / 64), dim3(512), 0, stream,
                           x, wpack, bf, bi, bc, bo, zx);
        hipLaunchKernelGGL(lstm_scan_res, dim3(8), dim3(512), 0, stream,
                           h0, c0, upack, zx, out);
    } else {
        hipLaunchKernelGGL(lstm_scan_fused, dim3(8), dim3(512), 0, stream,
                           x, h0, c0, bf, bi, bc, bo, upack, wpack, out);
    }
}